// Round 4
// baseline (108.922 us; speedup 1.0000x reference)
//
#include <hip/hip_runtime.h>
#include <hip/hip_bf16.h>
#include <hip/hip_fp16.h>

#define BB 16
#define TT 2048
#define DD 384
#define GG 2048          // total chains = BB * 128
#define CC 64            // chunks over T
#define LL 32            // steps per chunk (CC*LL == TT)
#define EPSF 1e-8f

// ---------- kernel 0: combined weights Wc[m][k][j] = sum_d W_in[k][d]*Wm[d][j] ----------
__global__ void precompute_wc(const float* __restrict__ W_in,
                              const float* __restrict__ W_biv,
                              const float* __restrict__ W_dec,
                              const float* __restrict__ W_inj,
                              float* __restrict__ Wc) {
    int idx = blockIdx.x * blockDim.x + threadIdx.x;  // 0 .. 3*DD-1
    if (idx >= 3 * DD) return;
    int m = idx / DD, j = idx - m * DD;
    const float* __restrict__ W = (m == 0) ? W_biv : (m == 1) ? W_dec : W_inj;
    float a0 = 0.f, a1 = 0.f, a2 = 0.f, a3 = 0.f;
    for (int d = 0; d < DD; ++d) {
        float wv = W[d * DD + j];
        a0 = fmaf(W_in[0 * DD + d], wv, a0);
        a1 = fmaf(W_in[1 * DD + d], wv, a1);
        a2 = fmaf(W_in[2 * DD + d], wv, a2);
        a3 = fmaf(W_in[3 * DD + d], wv, a3);
    }
    float* o = Wc + (size_t)m * 4 * DD + j;
    o[0 * DD] = a0; o[1 * DD] = a1; o[2 * DD] = a2; o[3 * DD] = a3;
}

// ---------- shared per-step math ----------
#define LOAD_CHAIN_WEIGHTS()                                        \
    const float* __restrict__ Wb = Wc;                              \
    const float* __restrict__ Wd = Wc + 4 * DD;                     \
    const float* __restrict__ Wi = Wc + 8 * DD;                     \
    float wb[4][3], wd[4][3], wi[4][3];                             \
    _Pragma("unroll")                                               \
    for (int k = 0; k < 4; ++k)                                     \
        _Pragma("unroll")                                           \
        for (int cth = 0; cth < 3; ++cth) {                         \
            wb[k][cth] = Wb[k * DD + j0 + cth];                     \
            wd[k][cth] = Wd[k * DD + j0 + cth];                     \
            wi[k][cth] = Wi[k * DD + j0 + cth];                     \
        }                                                           \
    float bbv[3], bdv[3], bjv[3];                                   \
    _Pragma("unroll")                                               \
    for (int cth = 0; cth < 3; ++cth) {                             \
        bbv[cth] = b_biv[j0 + cth];                                 \
        bdv[cth] = b_dec[j0 + cth];                                 \
        bjv[cth] = b_inj[j0 + cth];                                 \
    }

#define DOT4(W, c, bias) \
    fmaf(q.w, W[3][c], fmaf(q.z, W[2][c], fmaf(q.y, W[1][c], fmaf(q.x, W[0][c], bias))))

#define STEP_COMMON()                                               \
    float bx = DOT4(wb, 0, bbv[0]);                                 \
    float by = DOT4(wb, 1, bbv[1]);                                 \
    float bz = DOT4(wb, 2, bbv[2]);                                 \
    float d0 = DOT4(wd, 0, bdv[0]);                                 \
    float d1 = DOT4(wd, 1, bdv[1]);                                 \
    float d2 = DOT4(wd, 2, bdv[2]);                                 \
    float i0 = DOT4(wi, 0, bjv[0]);                                 \
    float i1 = DOT4(wi, 1, bjv[1]);                                 \
    float i2 = DOT4(wi, 2, bjv[2]);                                 \
    float dec0 = 1.f / (1.f + __expf(-d0));                         \
    float dec1 = 1.f / (1.f + __expf(-d1));                         \
    float dec2 = 1.f / (1.f + __expf(-d2));                         \
    float nb = fmaxf(sqrtf(fmaf(bx, bx, fmaf(by, by, bz * bz))), EPSF); \
    float half = 0.5f * nb;                                         \
    float w = __cosf(half);                                         \
    float s = __sinf(half) / nb;                                    \
    float qx = s * bz, qy = -s * by, qz = s * bx;

// ---------- kernel A: per-(chain, chunk) composed affine map ----------
__global__ __launch_bounds__(128) void chunk_compose(
        const float* __restrict__ quat,
        const float* __restrict__ Wc,
        const float* __restrict__ b_biv,
        const float* __restrict__ b_dec,
        const float* __restrict__ b_inj,
        float* __restrict__ Aff) {
    int c = blockIdx.x, b = blockIdx.y, n = threadIdx.x;
    int g = b * 128 + n, j0 = 3 * n;
    LOAD_CHAIN_WEIGHTS();

    float A[3][3] = {{1.f,0.f,0.f},{0.f,1.f,0.f},{0.f,0.f,1.f}};
    float dv[3] = {0.f, 0.f, 0.f};

    const float4* __restrict__ qp4 = (const float4*)(quat + (size_t)b * TT * 4) + c * LL;

    for (int t = 0; t < LL; ++t) {
        float4 q = qp4[t];
        STEP_COMMON();
        float xx = qx*qx, yy = qy*qy, zz = qz*qz;
        float xy = qx*qy, xz = qx*qz, yz = qy*qz;
        float wxs = w*qx, wys = w*qy, wzs = w*qz;
        float M[3][3];
        M[0][0] = dec0 * (1.f - 2.f*(yy+zz));
        M[0][1] = dec0 * (2.f*(xy - wzs));
        M[0][2] = dec0 * (2.f*(xz + wys));
        M[1][0] = dec1 * (2.f*(xy + wzs));
        M[1][1] = dec1 * (1.f - 2.f*(xx+zz));
        M[1][2] = dec1 * (2.f*(yz - wxs));
        M[2][0] = dec2 * (2.f*(xz - wys));
        M[2][1] = dec2 * (2.f*(yz + wxs));
        M[2][2] = dec2 * (1.f - 2.f*(xx+yy));
        float nA[3][3], nd[3];
#pragma unroll
        for (int i = 0; i < 3; ++i) {
#pragma unroll
            for (int j = 0; j < 3; ++j)
                nA[i][j] = fmaf(M[i][0], A[0][j], fmaf(M[i][1], A[1][j], M[i][2] * A[2][j]));
            nd[i] = fmaf(M[i][0], dv[0], fmaf(M[i][1], dv[1], M[i][2] * dv[2]));
        }
        nd[0] += i0; nd[1] += i1; nd[2] += i2;
#pragma unroll
        for (int i = 0; i < 3; ++i) {
#pragma unroll
            for (int j = 0; j < 3; ++j) A[i][j] = nA[i][j];
            dv[i] = nd[i];
        }
    }
    float4* o = (float4*)(Aff + ((size_t)c * GG + g) * 12);
    o[0] = make_float4(A[0][0], A[0][1], A[0][2], A[1][0]);
    o[1] = make_float4(A[1][1], A[1][2], A[2][0], A[2][1]);
    o[2] = make_float4(A[2][2], dv[0], dv[1], dv[2]);
}

// ---------- kernel B: serial prefix over chunks -> per-chunk starting h ----------
__global__ __launch_bounds__(256) void chunk_scan(
        const float* __restrict__ Aff,
        float* __restrict__ Hs) {
    int g = blockIdx.x * 256 + threadIdx.x;
    if (g >= GG) return;
    float h0 = 0.f, h1 = 0.f, h2 = 0.f;
#pragma unroll 4
    for (int c = 0; c < CC; ++c) {
        float* hs = Hs + ((size_t)c * GG + g) * 3;
        hs[0] = h0; hs[1] = h1; hs[2] = h2;
        const float4* a = (const float4*)(Aff + ((size_t)c * GG + g) * 12);
        float4 a0 = a[0], a1 = a[1], a2 = a[2];
        float n0 = fmaf(a0.x, h0, fmaf(a0.y, h1, fmaf(a0.z, h2, a2.y)));
        float n1 = fmaf(a0.w, h0, fmaf(a1.x, h1, fmaf(a1.y, h2, a2.z)));
        float n2 = fmaf(a1.z, h0, fmaf(a1.w, h1, fmaf(a2.x, h2, a2.w)));
        h0 = n0; h1 = n1; h2 = n2;
    }
}

// ---------- kernel C (new): replay chunk, store h as f16 — NO reduction, NO barriers ----------
__global__ __launch_bounds__(128) void chunk_apply(
        const float* __restrict__ quat,
        const float* __restrict__ Wc,
        const float* __restrict__ b_biv,
        const float* __restrict__ b_dec,
        const float* __restrict__ b_inj,
        const float* __restrict__ Hs,      // [CC][GG][3]
        __half* __restrict__ h_seq) {      // [BB][TT][DD]
    int c = blockIdx.x, b = blockIdx.y, n = threadIdx.x;
    int g = b * 128 + n, j0 = 3 * n;
    LOAD_CHAIN_WEIGHTS();

    const float* hs = Hs + ((size_t)c * GG + g) * 3;
    float vx = hs[0], vy = hs[1], vz = hs[2];

    const float4* __restrict__ qp4 = (const float4*)(quat + (size_t)b * TT * 4) + c * LL;
    __half* __restrict__ hp = h_seq + ((size_t)b * TT + (size_t)c * LL) * DD + j0;

    for (int t = 0; t < LL; ++t) {
        float4 q = qp4[t];
        STEP_COMMON();
        float tx = 2.f * (qy * vz - qz * vy);
        float ty = 2.f * (qz * vx - qx * vz);
        float tz = 2.f * (qx * vy - qy * vx);
        float rx = vx + w * tx + (qy * tz - qz * ty);
        float ry = vy + w * ty + (qz * tx - qx * tz);
        float rz = vz + w * tz + (qx * ty - qy * tx);
        vx = fmaf(dec0, rx, i0);
        vy = fmaf(dec1, ry, i1);
        vz = fmaf(dec2, rz, i2);
        __half* o = hp + (size_t)t * DD;
        o[0] = __float2half(vx);
        o[1] = __float2half(vy);
        o[2] = __float2half(vz);
    }
}

// ---------- kernel D: out = normalize(h_seq @ W_out), wave per (b,t) row ----------
__global__ __launch_bounds__(256) void out_kernel(
        const __half* __restrict__ h_seq,  // [BB*TT][DD]
        const float* __restrict__ W_out,   // [DD][4]
        float* __restrict__ out) {         // [BB*TT][4]
    int row = blockIdx.x * 4 + (threadIdx.x >> 6);
    int lane = threadIdx.x & 63;
    const __half* __restrict__ h = h_seq + (size_t)row * DD;
    float a0 = 0.f, a1 = 0.f, a2 = 0.f, a3 = 0.f;
#pragma unroll
    for (int d = lane; d < DD; d += 64) {
        float hv = __half2float(h[d]);
        float4 w = *(const float4*)(W_out + d * 4);
        a0 = fmaf(hv, w.x, a0);
        a1 = fmaf(hv, w.y, a1);
        a2 = fmaf(hv, w.z, a2);
        a3 = fmaf(hv, w.w, a3);
    }
#pragma unroll
    for (int off = 32; off; off >>= 1) {
        a0 += __shfl_xor(a0, off);
        a1 += __shfl_xor(a1, off);
        a2 += __shfl_xor(a2, off);
        a3 += __shfl_xor(a3, off);
    }
    if (lane == 0) {
        float norm = fmaxf(sqrtf(fmaf(a0, a0, fmaf(a1, a1, fmaf(a2, a2, a3 * a3)))), EPSF);
        float inv = 1.f / norm;
        *(float4*)(out + (size_t)row * 4) = make_float4(a0 * inv, a1 * inv, a2 * inv, a3 * inv);
    }
}

// ---------- fallback (fused reduce) — used only if workspace is too small ----------
__global__ __launch_bounds__(128) void chunk_apply_out(
        const float* __restrict__ quat,
        const float* __restrict__ Wc,
        const float* __restrict__ b_biv,
        const float* __restrict__ b_dec,
        const float* __restrict__ b_inj,
        const float* __restrict__ W_out,
        const float* __restrict__ Hs,
        float* __restrict__ out) {
    int c = blockIdx.x, b = blockIdx.y, n = threadIdx.x;
    int g = b * 128 + n, j0 = 3 * n;
    LOAD_CHAIN_WEIGHTS();

    float wo[3][4];
#pragma unroll
    for (int r = 0; r < 3; ++r) {
        float4 wv = *(const float4*)(W_out + (size_t)(j0 + r) * 4);
        wo[r][0] = wv.x; wo[r][1] = wv.y; wo[r][2] = wv.z; wo[r][3] = wv.w;
    }
    const float* hs = Hs + ((size_t)c * GG + g) * 3;
    float vx = hs[0], vy = hs[1], vz = hs[2];
    const float4* __restrict__ qp4 = (const float4*)(quat + (size_t)b * TT * 4) + c * LL;
    float* __restrict__ outp = out + ((size_t)b * TT + (size_t)c * LL) * 4;
    __shared__ float red[2][2][4];
    for (int t = 0; t < LL; ++t) {
        float4 q = qp4[t];
        STEP_COMMON();
        float tx = 2.f * (qy * vz - qz * vy);
        float ty = 2.f * (qz * vx - qx * vz);
        float tz = 2.f * (qx * vy - qy * vx);
        float rx = vx + w * tx + (qy * tz - qz * ty);
        float ry = vy + w * ty + (qz * tx - qx * tz);
        float rz = vz + w * tz + (qx * ty - qy * tx);
        vx = fmaf(dec0, rx, i0);
        vy = fmaf(dec1, ry, i1);
        vz = fmaf(dec2, rz, i2);
        float p0 = fmaf(vx, wo[0][0], fmaf(vy, wo[1][0], vz * wo[2][0]));
        float p1 = fmaf(vx, wo[0][1], fmaf(vy, wo[1][1], vz * wo[2][1]));
        float p2 = fmaf(vx, wo[0][2], fmaf(vy, wo[1][2], vz * wo[2][2]));
        float p3 = fmaf(vx, wo[0][3], fmaf(vy, wo[1][3], vz * wo[2][3]));
#pragma unroll
        for (int off = 32; off; off >>= 1) {
            p0 += __shfl_xor(p0, off);
            p1 += __shfl_xor(p1, off);
            p2 += __shfl_xor(p2, off);
            p3 += __shfl_xor(p3, off);
        }
        int wave = threadIdx.x >> 6;
        if ((threadIdx.x & 63) == 0) {
            red[t & 1][wave][0] = p0; red[t & 1][wave][1] = p1;
            red[t & 1][wave][2] = p2; red[t & 1][wave][3] = p3;
        }
        __syncthreads();
        if (threadIdx.x == 0) {
            float s0 = red[t & 1][0][0] + red[t & 1][1][0];
            float s1 = red[t & 1][0][1] + red[t & 1][1][1];
            float s2 = red[t & 1][0][2] + red[t & 1][1][2];
            float s3 = red[t & 1][0][3] + red[t & 1][1][3];
            float norm = fmaxf(sqrtf(fmaf(s0, s0, fmaf(s1, s1, fmaf(s2, s2, s3 * s3)))), EPSF);
            float inv = 1.f / norm;
            *(float4*)(outp + (size_t)t * 4) = make_float4(s0 * inv, s1 * inv, s2 * inv, s3 * inv);
        }
    }
}

extern "C" void kernel_launch(void* const* d_in, const int* in_sizes, int n_in,
                              void* d_out, int out_size, void* d_ws, size_t ws_size,
                              hipStream_t stream) {
    const float* quat  = (const float*)d_in[0];
    const float* W_in  = (const float*)d_in[1];
    const float* W_biv = (const float*)d_in[2];
    const float* b_biv = (const float*)d_in[3];
    const float* W_dec = (const float*)d_in[4];
    const float* b_dec = (const float*)d_in[5];
    const float* W_inj = (const float*)d_in[6];
    const float* b_inj = (const float*)d_in[7];
    const float* W_out = (const float*)d_in[8];
    float* out = (float*)d_out;

    const size_t AFF_OFF  = 32768;                                   // Wc: 18432 B
    const size_t AFF_B    = (size_t)CC * GG * 12 * sizeof(float);    // 6.29 MB
    const size_t HS_OFF   = AFF_OFF + AFF_B;
    const size_t HS_B     = (size_t)CC * GG * 3 * sizeof(float);     // 1.57 MB
    const size_t HSEQ_OFF = HS_OFF + HS_B;
    const size_t HSEQ_B   = (size_t)BB * TT * DD * sizeof(__half);   // 25.2 MB

    float* Wc  = (float*)d_ws;
    float* Aff = (float*)((char*)d_ws + AFF_OFF);
    float* Hs  = (float*)((char*)d_ws + HS_OFF);

    precompute_wc<<<dim3(9), dim3(128), 0, stream>>>(W_in, W_biv, W_dec, W_inj, Wc);
    chunk_compose<<<dim3(CC, BB), dim3(128), 0, stream>>>(quat, Wc, b_biv, b_dec, b_inj, Aff);
    chunk_scan<<<dim3(GG / 256), dim3(256), 0, stream>>>(Aff, Hs);

    if (ws_size >= HSEQ_OFF + HSEQ_B) {
        __half* h_seq = (__half*)((char*)d_ws + HSEQ_OFF);
        chunk_apply<<<dim3(CC, BB), dim3(128), 0, stream>>>(quat, Wc, b_biv, b_dec, b_inj,
                                                            Hs, h_seq);
        out_kernel<<<dim3(BB * TT / 4), dim3(256), 0, stream>>>(h_seq, W_out, out);
    } else {
        chunk_apply_out<<<dim3(CC, BB), dim3(128), 0, stream>>>(quat, Wc, b_biv, b_dec, b_inj,
                                                                W_out, Hs, out);
    }
}

// Round 5
// 84.175 us; speedup vs baseline: 1.2940x; 1.2940x over previous
//
#include <hip/hip_runtime.h>
#include <hip/hip_bf16.h>

#define BB 16
#define TT 2048
#define DD 384
#define GG 2048          // total chains = BB * 128
#define CC 64            // chunks over T
#define LL 32            // steps per chunk (CC*LL == TT)
#define EPSF 1e-8f

// ---------- kernel 0: combined weights Wc[m][k][j] = sum_d W_in[k][d]*Wm[d][j] ----------
// grid (3, DD/16), block 256 = 16 j-lanes x 16 d-parts; LDS tree reduce over d-parts.
__global__ __launch_bounds__(256) void precompute_wc(
        const float* __restrict__ W_in,
        const float* __restrict__ W_biv,
        const float* __restrict__ W_dec,
        const float* __restrict__ W_inj,
        float* __restrict__ Wc) {
    int m = blockIdx.x;
    int jl = threadIdx.x & 15;
    int dp = threadIdx.x >> 4;           // 0..15
    int j = blockIdx.y * 16 + jl;
    const float* __restrict__ W = (m == 0) ? W_biv : (m == 1) ? W_dec : W_inj;
    float a[4] = {0.f, 0.f, 0.f, 0.f};
    for (int d = dp; d < DD; d += 16) {
        float wv = W[d * DD + j];
#pragma unroll
        for (int k = 0; k < 4; ++k) a[k] = fmaf(W_in[k * DD + d], wv, a[k]);
    }
    __shared__ float red[16][17][4];
#pragma unroll
    for (int k = 0; k < 4; ++k) red[dp][jl][k] = a[k];
    __syncthreads();
    for (int s = 8; s >= 1; s >>= 1) {
        if (dp < s) {
#pragma unroll
            for (int k = 0; k < 4; ++k) red[dp][jl][k] += red[dp + s][jl][k];
        }
        __syncthreads();
    }
    if (dp < 4)  // dp plays role of k now
        Wc[(size_t)m * 4 * DD + dp * DD + j] = red[0][jl][dp];
}

// ---------- shared per-step math ----------
#define LOAD_CHAIN_WEIGHTS()                                        \
    const float* __restrict__ Wb = Wc;                              \
    const float* __restrict__ Wd = Wc + 4 * DD;                     \
    const float* __restrict__ Wi = Wc + 8 * DD;                     \
    float wb[4][3], wd[4][3], wi[4][3];                             \
    _Pragma("unroll")                                               \
    for (int k = 0; k < 4; ++k)                                     \
        _Pragma("unroll")                                           \
        for (int cth = 0; cth < 3; ++cth) {                         \
            wb[k][cth] = Wb[k * DD + j0 + cth];                     \
            wd[k][cth] = Wd[k * DD + j0 + cth];                     \
            wi[k][cth] = Wi[k * DD + j0 + cth];                     \
        }                                                           \
    float bbv[3], bdv[3], bjv[3];                                   \
    _Pragma("unroll")                                               \
    for (int cth = 0; cth < 3; ++cth) {                             \
        bbv[cth] = b_biv[j0 + cth];                                 \
        bdv[cth] = b_dec[j0 + cth];                                 \
        bjv[cth] = b_inj[j0 + cth];                                 \
    }

#define DOT4(W, c, bias) \
    fmaf(q.w, W[3][c], fmaf(q.z, W[2][c], fmaf(q.y, W[1][c], fmaf(q.x, W[0][c], bias))))

#define STEP_COMMON()                                               \
    float bx = DOT4(wb, 0, bbv[0]);                                 \
    float by = DOT4(wb, 1, bbv[1]);                                 \
    float bz = DOT4(wb, 2, bbv[2]);                                 \
    float d0 = DOT4(wd, 0, bdv[0]);                                 \
    float d1 = DOT4(wd, 1, bdv[1]);                                 \
    float d2 = DOT4(wd, 2, bdv[2]);                                 \
    float i0 = DOT4(wi, 0, bjv[0]);                                 \
    float i1 = DOT4(wi, 1, bjv[1]);                                 \
    float i2 = DOT4(wi, 2, bjv[2]);                                 \
    float dec0 = 1.f / (1.f + __expf(-d0));                         \
    float dec1 = 1.f / (1.f + __expf(-d1));                         \
    float dec2 = 1.f / (1.f + __expf(-d2));                         \
    float nb = fmaxf(sqrtf(fmaf(bx, bx, fmaf(by, by, bz * bz))), EPSF); \
    float half = 0.5f * nb;                                         \
    float w = __cosf(half);                                         \
    float s = __sinf(half) / nb;                                    \
    float qx = s * bz, qy = -s * by, qz = s * bx;

// ---------- kernel A: per-(chain, chunk) composed affine map ----------
// Aff layout: [CC][GG][12]
__global__ __launch_bounds__(128) void chunk_compose(
        const float* __restrict__ quat,
        const float* __restrict__ Wc,
        const float* __restrict__ b_biv,
        const float* __restrict__ b_dec,
        const float* __restrict__ b_inj,
        float* __restrict__ Aff) {
    int c = blockIdx.x, b = blockIdx.y, n = threadIdx.x;
    int g = b * 128 + n, j0 = 3 * n;
    LOAD_CHAIN_WEIGHTS();

    float A[3][3] = {{1.f,0.f,0.f},{0.f,1.f,0.f},{0.f,0.f,1.f}};
    float dv[3] = {0.f, 0.f, 0.f};

    const float4* __restrict__ qp4 = (const float4*)(quat + (size_t)b * TT * 4) + c * LL;

    for (int t = 0; t < LL; ++t) {
        float4 q = qp4[t];
        STEP_COMMON();
        float xx = qx*qx, yy = qy*qy, zz = qz*qz;
        float xy = qx*qy, xz = qx*qz, yz = qy*qz;
        float wxs = w*qx, wys = w*qy, wzs = w*qz;
        float M[3][3];
        M[0][0] = dec0 * (1.f - 2.f*(yy+zz));
        M[0][1] = dec0 * (2.f*(xy - wzs));
        M[0][2] = dec0 * (2.f*(xz + wys));
        M[1][0] = dec1 * (2.f*(xy + wzs));
        M[1][1] = dec1 * (1.f - 2.f*(xx+zz));
        M[1][2] = dec1 * (2.f*(yz - wxs));
        M[2][0] = dec2 * (2.f*(xz - wys));
        M[2][1] = dec2 * (2.f*(yz + wxs));
        M[2][2] = dec2 * (1.f - 2.f*(xx+yy));
        float nA[3][3], nd[3];
#pragma unroll
        for (int i = 0; i < 3; ++i) {
#pragma unroll
            for (int j = 0; j < 3; ++j)
                nA[i][j] = fmaf(M[i][0], A[0][j], fmaf(M[i][1], A[1][j], M[i][2] * A[2][j]));
            nd[i] = fmaf(M[i][0], dv[0], fmaf(M[i][1], dv[1], M[i][2] * dv[2]));
        }
        nd[0] += i0; nd[1] += i1; nd[2] += i2;
#pragma unroll
        for (int i = 0; i < 3; ++i) {
#pragma unroll
            for (int j = 0; j < 3; ++j) A[i][j] = nA[i][j];
            dv[i] = nd[i];
        }
    }
    float4* o = (float4*)(Aff + ((size_t)c * GG + g) * 12);
    o[0] = make_float4(A[0][0], A[0][1], A[0][2], A[1][0]);
    o[1] = make_float4(A[1][1], A[1][2], A[2][0], A[2][1]);
    o[2] = make_float4(A[2][2], dv[0], dv[1], dv[2]);
}

// ---------- kernel B: wave-parallel Kogge-Stone scan over chunks ----------
// one wave per chain; lane c holds chunk c's map; exclusive prefix -> Hs[c][g][3]
__global__ __launch_bounds__(256) void chunk_scan(
        const float* __restrict__ Aff,
        float* __restrict__ Hs) {
    int g = (blockIdx.x * 256 + threadIdx.x) >> 6;   // chain
    int c = threadIdx.x & 63;                        // chunk = lane
    const float4* a = (const float4*)(Aff + ((size_t)c * GG + g) * 12);
    float4 a0 = a[0], a1 = a[1], a2 = a[2];
    float A00=a0.x, A01=a0.y, A02=a0.z, A10=a0.w, A11=a1.x, A12=a1.y;
    float A20=a1.z, A21=a1.w, A22=a2.x, d0=a2.y, d1=a2.z, d2=a2.w;

    // shift up by 1 (exclusive); lane 0 = identity
    A00 = __shfl_up(A00, 1); A01 = __shfl_up(A01, 1); A02 = __shfl_up(A02, 1);
    A10 = __shfl_up(A10, 1); A11 = __shfl_up(A11, 1); A12 = __shfl_up(A12, 1);
    A20 = __shfl_up(A20, 1); A21 = __shfl_up(A21, 1); A22 = __shfl_up(A22, 1);
    d0  = __shfl_up(d0, 1);  d1  = __shfl_up(d1, 1);  d2  = __shfl_up(d2, 1);
    if (c == 0) {
        A00 = 1.f; A01 = 0.f; A02 = 0.f;
        A10 = 0.f; A11 = 1.f; A12 = 0.f;
        A20 = 0.f; A21 = 0.f; A22 = 1.f;
        d0 = 0.f; d1 = 0.f; d2 = 0.f;
    }

#pragma unroll
    for (int sft = 1; sft < 64; sft <<= 1) {
        float pA00 = __shfl_up(A00, sft), pA01 = __shfl_up(A01, sft), pA02 = __shfl_up(A02, sft);
        float pA10 = __shfl_up(A10, sft), pA11 = __shfl_up(A11, sft), pA12 = __shfl_up(A12, sft);
        float pA20 = __shfl_up(A20, sft), pA21 = __shfl_up(A21, sft), pA22 = __shfl_up(A22, sft);
        float pd0  = __shfl_up(d0, sft),  pd1  = __shfl_up(d1, sft),  pd2  = __shfl_up(d2, sft);
        bool act = (c >= sft);
        // new = cur ∘ prev
        float nA00 = fmaf(A00, pA00, fmaf(A01, pA10, A02 * pA20));
        float nA01 = fmaf(A00, pA01, fmaf(A01, pA11, A02 * pA21));
        float nA02 = fmaf(A00, pA02, fmaf(A01, pA12, A02 * pA22));
        float nA10 = fmaf(A10, pA00, fmaf(A11, pA10, A12 * pA20));
        float nA11 = fmaf(A10, pA01, fmaf(A11, pA11, A12 * pA21));
        float nA12 = fmaf(A10, pA02, fmaf(A11, pA12, A12 * pA22));
        float nA20 = fmaf(A20, pA00, fmaf(A21, pA10, A22 * pA20));
        float nA21 = fmaf(A20, pA01, fmaf(A21, pA11, A22 * pA21));
        float nA22 = fmaf(A20, pA02, fmaf(A21, pA12, A22 * pA22));
        float nd0  = fmaf(A00, pd0, fmaf(A01, pd1, fmaf(A02, pd2, d0)));
        float nd1  = fmaf(A10, pd0, fmaf(A11, pd1, fmaf(A12, pd2, d1)));
        float nd2  = fmaf(A20, pd0, fmaf(A21, pd1, fmaf(A22, pd2, d2)));
        A00 = act ? nA00 : A00; A01 = act ? nA01 : A01; A02 = act ? nA02 : A02;
        A10 = act ? nA10 : A10; A11 = act ? nA11 : A11; A12 = act ? nA12 : A12;
        A20 = act ? nA20 : A20; A21 = act ? nA21 : A21; A22 = act ? nA22 : A22;
        d0  = act ? nd0  : d0;  d1  = act ? nd1  : d1;  d2  = act ? nd2  : d2;
    }
    // h start of chunk c = translation part (h0 = 0)
    float* hs = Hs + ((size_t)c * GG + g) * 3;
    hs[0] = d0; hs[1] = d1; hs[2] = d2;
}

// ---------- kernel C: fused replay + out-projection via LDS, ONE barrier ----------
__global__ __launch_bounds__(128) void chunk_apply_out(
        const float* __restrict__ quat,
        const float* __restrict__ Wc,
        const float* __restrict__ b_biv,
        const float* __restrict__ b_dec,
        const float* __restrict__ b_inj,
        const float* __restrict__ W_out,   // [DD][4]
        const float* __restrict__ Hs,      // [CC][GG][3]
        float* __restrict__ out) {         // [BB][TT][4]
    int c = blockIdx.x, b = blockIdx.y, n = threadIdx.x;
    int g = b * 128 + n, j0 = 3 * n;
    LOAD_CHAIN_WEIGHTS();

    __shared__ float H[LL][DD + 1];   // padded stride 385 words

    const float* hs = Hs + ((size_t)c * GG + g) * 3;
    float vx = hs[0], vy = hs[1], vz = hs[2];

    const float4* __restrict__ qp4 = (const float4*)(quat + (size_t)b * TT * 4) + c * LL;

    for (int t = 0; t < LL; ++t) {
        float4 q = qp4[t];
        STEP_COMMON();
        float tx = 2.f * (qy * vz - qz * vy);
        float ty = 2.f * (qz * vx - qx * vz);
        float tz = 2.f * (qx * vy - qy * vx);
        float rx = vx + w * tx + (qy * tz - qz * ty);
        float ry = vy + w * ty + (qz * tx - qx * tz);
        float rz = vz + w * tz + (qx * ty - qy * tx);
        vx = fmaf(dec0, rx, i0);
        vy = fmaf(dec1, ry, i1);
        vz = fmaf(dec2, rz, i2);
        H[t][j0] = vx; H[t][j0 + 1] = vy; H[t][j0 + 2] = vz;
    }
    __syncthreads();

    // projection: thread -> (row r, quarter p); d = p + 4j
    int r = n >> 2, p = n & 3;
    float s0 = 0.f, s1 = 0.f, s2 = 0.f, s3 = 0.f;
#pragma unroll 8
    for (int j = 0; j < DD / 4; ++j) {
        int d = p + 4 * j;
        float hv = H[r][d];
        float4 wv = *(const float4*)(W_out + (size_t)d * 4);
        s0 = fmaf(hv, wv.x, s0);
        s1 = fmaf(hv, wv.y, s1);
        s2 = fmaf(hv, wv.z, s2);
        s3 = fmaf(hv, wv.w, s3);
    }
#pragma unroll
    for (int off = 1; off <= 2; off <<= 1) {
        s0 += __shfl_xor(s0, off);
        s1 += __shfl_xor(s1, off);
        s2 += __shfl_xor(s2, off);
        s3 += __shfl_xor(s3, off);
    }
    if (p == 0) {
        float norm = fmaxf(sqrtf(fmaf(s0, s0, fmaf(s1, s1, fmaf(s2, s2, s3 * s3)))), EPSF);
        float inv = 1.f / norm;
        float* outp = out + ((size_t)b * TT + (size_t)c * LL + r) * 4;
        *(float4*)outp = make_float4(s0 * inv, s1 * inv, s2 * inv, s3 * inv);
    }
}

extern "C" void kernel_launch(void* const* d_in, const int* in_sizes, int n_in,
                              void* d_out, int out_size, void* d_ws, size_t ws_size,
                              hipStream_t stream) {
    const float* quat  = (const float*)d_in[0];
    const float* W_in  = (const float*)d_in[1];
    const float* W_biv = (const float*)d_in[2];
    const float* b_biv = (const float*)d_in[3];
    const float* W_dec = (const float*)d_in[4];
    const float* b_dec = (const float*)d_in[5];
    const float* W_inj = (const float*)d_in[6];
    const float* b_inj = (const float*)d_in[7];
    const float* W_out = (const float*)d_in[8];
    float* out = (float*)d_out;

    const size_t AFF_OFF = 32768;                                  // Wc: 18432 B
    const size_t AFF_B   = (size_t)CC * GG * 12 * sizeof(float);   // 6.29 MB
    const size_t HS_OFF  = AFF_OFF + AFF_B;

    float* Wc  = (float*)d_ws;
    float* Aff = (float*)((char*)d_ws + AFF_OFF);
    float* Hs  = (float*)((char*)d_ws + HS_OFF);

    precompute_wc<<<dim3(3, DD / 16), dim3(256), 0, stream>>>(W_in, W_biv, W_dec, W_inj, Wc);
    chunk_compose<<<dim3(CC, BB), dim3(128), 0, stream>>>(quat, Wc, b_biv, b_dec, b_inj, Aff);
    chunk_scan<<<dim3(GG / 4), dim3(256), 0, stream>>>(Aff, Hs);
    chunk_apply_out<<<dim3(CC, BB), dim3(128), 0, stream>>>(quat, Wc, b_biv, b_dec, b_inj,
                                                            W_out, Hs, out);
}

// Round 6
// 78.307 us; speedup vs baseline: 1.3910x; 1.0749x over previous
//
#include <hip/hip_runtime.h>
#include <hip/hip_bf16.h>

#define BB 16
#define TT 2048
#define DD 384
#define GG 2048          // total chains = BB * 128
#define CC 128           // chunks over T
#define LL 16            // steps per chunk (CC*LL == TT)
#define HSTRIDE (DD + 8) // 392: ≡8 mod 32 -> conflict-free LDS writes & reads
#define EPSF 1e-8f

// ---------- kernel 0: combined weights Wc[m][k][j] = sum_d W_in[k][d]*Wm[d][j] ----------
__global__ __launch_bounds__(256) void precompute_wc(
        const float* __restrict__ W_in,
        const float* __restrict__ W_biv,
        const float* __restrict__ W_dec,
        const float* __restrict__ W_inj,
        float* __restrict__ Wc) {
    int m = blockIdx.x;
    int jl = threadIdx.x & 15;
    int dp = threadIdx.x >> 4;           // 0..15
    int j = blockIdx.y * 16 + jl;
    const float* __restrict__ W = (m == 0) ? W_biv : (m == 1) ? W_dec : W_inj;
    float a[4] = {0.f, 0.f, 0.f, 0.f};
    for (int d = dp; d < DD; d += 16) {
        float wv = W[d * DD + j];
#pragma unroll
        for (int k = 0; k < 4; ++k) a[k] = fmaf(W_in[k * DD + d], wv, a[k]);
    }
    __shared__ float red[16][17][4];
#pragma unroll
    for (int k = 0; k < 4; ++k) red[dp][jl][k] = a[k];
    __syncthreads();
    for (int s = 8; s >= 1; s >>= 1) {
        if (dp < s) {
#pragma unroll
            for (int k = 0; k < 4; ++k) red[dp][jl][k] += red[dp + s][jl][k];
        }
        __syncthreads();
    }
    if (dp < 4)
        Wc[(size_t)m * 4 * DD + dp * DD + j] = red[0][jl][dp];
}

// ---------- shared per-step math ----------
#define LOAD_CHAIN_WEIGHTS()                                        \
    const float* __restrict__ Wb = Wc;                              \
    const float* __restrict__ Wd = Wc + 4 * DD;                     \
    const float* __restrict__ Wi = Wc + 8 * DD;                     \
    float wb[4][3], wd[4][3], wi[4][3];                             \
    _Pragma("unroll")                                               \
    for (int k = 0; k < 4; ++k)                                     \
        _Pragma("unroll")                                           \
        for (int cth = 0; cth < 3; ++cth) {                         \
            wb[k][cth] = Wb[k * DD + j0 + cth];                     \
            wd[k][cth] = Wd[k * DD + j0 + cth];                     \
            wi[k][cth] = Wi[k * DD + j0 + cth];                     \
        }                                                           \
    float bbv[3], bdv[3], bjv[3];                                   \
    _Pragma("unroll")                                               \
    for (int cth = 0; cth < 3; ++cth) {                             \
        bbv[cth] = b_biv[j0 + cth];                                 \
        bdv[cth] = b_dec[j0 + cth];                                 \
        bjv[cth] = b_inj[j0 + cth];                                 \
    }

#define DOT4(W, c, bias) \
    fmaf(q.w, W[3][c], fmaf(q.z, W[2][c], fmaf(q.y, W[1][c], fmaf(q.x, W[0][c], bias))))

#define STEP_COMMON()                                               \
    float bx = DOT4(wb, 0, bbv[0]);                                 \
    float by = DOT4(wb, 1, bbv[1]);                                 \
    float bz = DOT4(wb, 2, bbv[2]);                                 \
    float d0 = DOT4(wd, 0, bdv[0]);                                 \
    float d1 = DOT4(wd, 1, bdv[1]);                                 \
    float d2 = DOT4(wd, 2, bdv[2]);                                 \
    float i0 = DOT4(wi, 0, bjv[0]);                                 \
    float i1 = DOT4(wi, 1, bjv[1]);                                 \
    float i2 = DOT4(wi, 2, bjv[2]);                                 \
    float dec0 = 1.f / (1.f + __expf(-d0));                         \
    float dec1 = 1.f / (1.f + __expf(-d1));                         \
    float dec2 = 1.f / (1.f + __expf(-d2));                         \
    float nb = fmaxf(sqrtf(fmaf(bx, bx, fmaf(by, by, bz * bz))), EPSF); \
    float half = 0.5f * nb;                                         \
    float w = __cosf(half);                                         \
    float s = __sinf(half) / nb;                                    \
    float qx = s * bz, qy = -s * by, qz = s * bx;

// ---------- kernel A: per-(chain, chunk) composed affine map ----------
// Aff layout: [CC][GG][12]
__global__ __launch_bounds__(128) void chunk_compose(
        const float* __restrict__ quat,
        const float* __restrict__ Wc,
        const float* __restrict__ b_biv,
        const float* __restrict__ b_dec,
        const float* __restrict__ b_inj,
        float* __restrict__ Aff) {
    int c = blockIdx.x, b = blockIdx.y, n = threadIdx.x;
    int g = b * 128 + n, j0 = 3 * n;
    LOAD_CHAIN_WEIGHTS();

    float A[3][3] = {{1.f,0.f,0.f},{0.f,1.f,0.f},{0.f,0.f,1.f}};
    float dv[3] = {0.f, 0.f, 0.f};

    const float4* __restrict__ qp4 = (const float4*)(quat + (size_t)b * TT * 4) + c * LL;

    for (int t = 0; t < LL; ++t) {
        float4 q = qp4[t];
        STEP_COMMON();
        float xx = qx*qx, yy = qy*qy, zz = qz*qz;
        float xy = qx*qy, xz = qx*qz, yz = qy*qz;
        float wxs = w*qx, wys = w*qy, wzs = w*qz;
        float M[3][3];
        M[0][0] = dec0 * (1.f - 2.f*(yy+zz));
        M[0][1] = dec0 * (2.f*(xy - wzs));
        M[0][2] = dec0 * (2.f*(xz + wys));
        M[1][0] = dec1 * (2.f*(xy + wzs));
        M[1][1] = dec1 * (1.f - 2.f*(xx+zz));
        M[1][2] = dec1 * (2.f*(yz - wxs));
        M[2][0] = dec2 * (2.f*(xz - wys));
        M[2][1] = dec2 * (2.f*(yz + wxs));
        M[2][2] = dec2 * (1.f - 2.f*(xx+yy));
        float nA[3][3], nd[3];
#pragma unroll
        for (int i = 0; i < 3; ++i) {
#pragma unroll
            for (int j = 0; j < 3; ++j)
                nA[i][j] = fmaf(M[i][0], A[0][j], fmaf(M[i][1], A[1][j], M[i][2] * A[2][j]));
            nd[i] = fmaf(M[i][0], dv[0], fmaf(M[i][1], dv[1], M[i][2] * dv[2]));
        }
        nd[0] += i0; nd[1] += i1; nd[2] += i2;
#pragma unroll
        for (int i = 0; i < 3; ++i) {
#pragma unroll
            for (int j = 0; j < 3; ++j) A[i][j] = nA[i][j];
            dv[i] = nd[i];
        }
    }
    float4* o = (float4*)(Aff + ((size_t)c * GG + g) * 12);
    o[0] = make_float4(A[0][0], A[0][1], A[0][2], A[1][0]);
    o[1] = make_float4(A[1][1], A[1][2], A[2][0], A[2][1]);
    o[2] = make_float4(A[2][2], dv[0], dv[1], dv[2]);
}

// ---------- kernel B: wave-parallel scan over 128 chunks (2 per lane) ----------
// lane l pair-composes chunks (2l, 2l+1); Kogge-Stone exclusive over pair maps;
// emits start-state of both chunks into Hs[c][g][3].
__global__ __launch_bounds__(256) void chunk_scan(
        const float* __restrict__ Aff,
        float* __restrict__ Hs) {
    int g = (blockIdx.x * 256 + threadIdx.x) >> 6;   // chain
    int l = threadIdx.x & 63;                        // lane = chunk pair

    // load even map (chunk 2l)
    const float4* aE = (const float4*)(Aff + ((size_t)(2 * l) * GG + g) * 12);
    float4 e0 = aE[0], e1 = aE[1], e2 = aE[2];
    float E00=e0.x, E01=e0.y, E02=e0.z, E10=e0.w, E11=e1.x, E12=e1.y;
    float E20=e1.z, E21=e1.w, E22=e2.x, ed0=e2.y, ed1=e2.z, ed2=e2.w;
    // load odd map (chunk 2l+1)
    const float4* aO = (const float4*)(Aff + ((size_t)(2 * l + 1) * GG + g) * 12);
    float4 o0 = aO[0], o1 = aO[1], o2 = aO[2];
    float O00=o0.x, O01=o0.y, O02=o0.z, O10=o0.w, O11=o1.x, O12=o1.y;
    float O20=o1.z, O21=o1.w, O22=o2.x, od0=o2.y, od1=o2.z, od2=o2.w;

    // pair = odd ∘ even
    float A00 = fmaf(O00, E00, fmaf(O01, E10, O02 * E20));
    float A01 = fmaf(O00, E01, fmaf(O01, E11, O02 * E21));
    float A02 = fmaf(O00, E02, fmaf(O01, E12, O02 * E22));
    float A10 = fmaf(O10, E00, fmaf(O11, E10, O12 * E20));
    float A11 = fmaf(O10, E01, fmaf(O11, E11, O12 * E21));
    float A12 = fmaf(O10, E02, fmaf(O11, E12, O12 * E22));
    float A20 = fmaf(O20, E00, fmaf(O21, E10, O22 * E20));
    float A21 = fmaf(O20, E01, fmaf(O21, E11, O22 * E21));
    float A22 = fmaf(O20, E02, fmaf(O21, E12, O22 * E22));
    float d0  = fmaf(O00, ed0, fmaf(O01, ed1, fmaf(O02, ed2, od0)));
    float d1  = fmaf(O10, ed0, fmaf(O11, ed1, fmaf(O12, ed2, od1)));
    float d2  = fmaf(O20, ed0, fmaf(O21, ed1, fmaf(O22, ed2, od2)));

    // shift up by 1 (exclusive); lane 0 = identity
    A00 = __shfl_up(A00, 1); A01 = __shfl_up(A01, 1); A02 = __shfl_up(A02, 1);
    A10 = __shfl_up(A10, 1); A11 = __shfl_up(A11, 1); A12 = __shfl_up(A12, 1);
    A20 = __shfl_up(A20, 1); A21 = __shfl_up(A21, 1); A22 = __shfl_up(A22, 1);
    d0  = __shfl_up(d0, 1);  d1  = __shfl_up(d1, 1);  d2  = __shfl_up(d2, 1);
    if (l == 0) {
        A00 = 1.f; A01 = 0.f; A02 = 0.f;
        A10 = 0.f; A11 = 1.f; A12 = 0.f;
        A20 = 0.f; A21 = 0.f; A22 = 1.f;
        d0 = 0.f; d1 = 0.f; d2 = 0.f;
    }

#pragma unroll
    for (int sft = 1; sft < 64; sft <<= 1) {
        float pA00 = __shfl_up(A00, sft), pA01 = __shfl_up(A01, sft), pA02 = __shfl_up(A02, sft);
        float pA10 = __shfl_up(A10, sft), pA11 = __shfl_up(A11, sft), pA12 = __shfl_up(A12, sft);
        float pA20 = __shfl_up(A20, sft), pA21 = __shfl_up(A21, sft), pA22 = __shfl_up(A22, sft);
        float pd0  = __shfl_up(d0, sft),  pd1  = __shfl_up(d1, sft),  pd2  = __shfl_up(d2, sft);
        bool act = (l >= sft);
        float nA00 = fmaf(A00, pA00, fmaf(A01, pA10, A02 * pA20));
        float nA01 = fmaf(A00, pA01, fmaf(A01, pA11, A02 * pA21));
        float nA02 = fmaf(A00, pA02, fmaf(A01, pA12, A02 * pA22));
        float nA10 = fmaf(A10, pA00, fmaf(A11, pA10, A12 * pA20));
        float nA11 = fmaf(A10, pA01, fmaf(A11, pA11, A12 * pA21));
        float nA12 = fmaf(A10, pA02, fmaf(A11, pA12, A12 * pA22));
        float nA20 = fmaf(A20, pA00, fmaf(A21, pA10, A22 * pA20));
        float nA21 = fmaf(A20, pA01, fmaf(A21, pA11, A22 * pA21));
        float nA22 = fmaf(A20, pA02, fmaf(A21, pA12, A22 * pA22));
        float nd0  = fmaf(A00, pd0, fmaf(A01, pd1, fmaf(A02, pd2, d0)));
        float nd1  = fmaf(A10, pd0, fmaf(A11, pd1, fmaf(A12, pd2, d1)));
        float nd2  = fmaf(A20, pd0, fmaf(A21, pd1, fmaf(A22, pd2, d2)));
        A00 = act ? nA00 : A00; A01 = act ? nA01 : A01; A02 = act ? nA02 : A02;
        A10 = act ? nA10 : A10; A11 = act ? nA11 : A11; A12 = act ? nA12 : A12;
        A20 = act ? nA20 : A20; A21 = act ? nA21 : A21; A22 = act ? nA22 : A22;
        d0  = act ? nd0  : d0;  d1  = act ? nd1  : d1;  d2  = act ? nd2  : d2;
    }
    // start of chunk 2l: h = d (h0 = 0);  start of chunk 2l+1: even map applied
    float* hsE = Hs + ((size_t)(2 * l) * GG + g) * 3;
    hsE[0] = d0; hsE[1] = d1; hsE[2] = d2;
    float h0o = fmaf(E00, d0, fmaf(E01, d1, fmaf(E02, d2, ed0)));
    float h1o = fmaf(E10, d0, fmaf(E11, d1, fmaf(E12, d2, ed1)));
    float h2o = fmaf(E20, d0, fmaf(E21, d1, fmaf(E22, d2, ed2)));
    float* hsO = Hs + ((size_t)(2 * l + 1) * GG + g) * 3;
    hsO[0] = h0o; hsO[1] = h1o; hsO[2] = h2o;
}

// ---------- kernel C: fused replay + out-projection via LDS, ONE barrier ----------
__global__ __launch_bounds__(128) void chunk_apply_out(
        const float* __restrict__ quat,
        const float* __restrict__ Wc,
        const float* __restrict__ b_biv,
        const float* __restrict__ b_dec,
        const float* __restrict__ b_inj,
        const float* __restrict__ W_out,   // [DD][4]
        const float* __restrict__ Hs,      // [CC][GG][3]
        float* __restrict__ out) {         // [BB][TT][4]
    int c = blockIdx.x, b = blockIdx.y, n = threadIdx.x;
    int g = b * 128 + n, j0 = 3 * n;
    LOAD_CHAIN_WEIGHTS();

    __shared__ float H[LL][HSTRIDE];   // stride 392 ≡ 8 (mod 32): conflict-free

    const float* hs = Hs + ((size_t)c * GG + g) * 3;
    float vx = hs[0], vy = hs[1], vz = hs[2];

    const float4* __restrict__ qp4 = (const float4*)(quat + (size_t)b * TT * 4) + c * LL;

    for (int t = 0; t < LL; ++t) {
        float4 q = qp4[t];
        STEP_COMMON();
        float tx = 2.f * (qy * vz - qz * vy);
        float ty = 2.f * (qz * vx - qx * vz);
        float tz = 2.f * (qx * vy - qy * vx);
        float rx = vx + w * tx + (qy * tz - qz * ty);
        float ry = vy + w * ty + (qz * tx - qx * tz);
        float rz = vz + w * tz + (qx * ty - qy * tx);
        vx = fmaf(dec0, rx, i0);
        vy = fmaf(dec1, ry, i1);
        vz = fmaf(dec2, rz, i2);
        H[t][j0] = vx; H[t][j0 + 1] = vy; H[t][j0 + 2] = vz;
    }
    __syncthreads();

    // projection: thread -> (row r, part p); d = p + 8j
    int r = n >> 3, p = n & 7;
    float s0 = 0.f, s1 = 0.f, s2 = 0.f, s3 = 0.f;
#pragma unroll 8
    for (int j = 0; j < DD / 8; ++j) {
        int d = p + 8 * j;
        float hv = H[r][d];
        float4 wv = *(const float4*)(W_out + (size_t)d * 4);
        s0 = fmaf(hv, wv.x, s0);
        s1 = fmaf(hv, wv.y, s1);
        s2 = fmaf(hv, wv.z, s2);
        s3 = fmaf(hv, wv.w, s3);
    }
#pragma unroll
    for (int off = 1; off <= 4; off <<= 1) {
        s0 += __shfl_xor(s0, off);
        s1 += __shfl_xor(s1, off);
        s2 += __shfl_xor(s2, off);
        s3 += __shfl_xor(s3, off);
    }
    if (p == 0) {
        float norm = fmaxf(sqrtf(fmaf(s0, s0, fmaf(s1, s1, fmaf(s2, s2, s3 * s3)))), EPSF);
        float inv = 1.f / norm;
        float* outp = out + ((size_t)b * TT + (size_t)c * LL + r) * 4;
        *(float4*)outp = make_float4(s0 * inv, s1 * inv, s2 * inv, s3 * inv);
    }
}

extern "C" void kernel_launch(void* const* d_in, const int* in_sizes, int n_in,
                              void* d_out, int out_size, void* d_ws, size_t ws_size,
                              hipStream_t stream) {
    const float* quat  = (const float*)d_in[0];
    const float* W_in  = (const float*)d_in[1];
    const float* W_biv = (const float*)d_in[2];
    const float* b_biv = (const float*)d_in[3];
    const float* W_dec = (const float*)d_in[4];
    const float* b_dec = (const float*)d_in[5];
    const float* W_inj = (const float*)d_in[6];
    const float* b_inj = (const float*)d_in[7];
    const float* W_out = (const float*)d_in[8];
    float* out = (float*)d_out;

    const size_t AFF_OFF = 32768;                                  // Wc: 18432 B
    const size_t AFF_B   = (size_t)CC * GG * 12 * sizeof(float);   // 12.58 MB
    const size_t HS_OFF  = AFF_OFF + AFF_B;

    float* Wc  = (float*)d_ws;
    float* Aff = (float*)((char*)d_ws + AFF_OFF);
    float* Hs  = (float*)((char*)d_ws + HS_OFF);

    precompute_wc<<<dim3(3, DD / 16), dim3(256), 0, stream>>>(W_in, W_biv, W_dec, W_inj, Wc);
    chunk_compose<<<dim3(CC, BB), dim3(128), 0, stream>>>(quat, Wc, b_biv, b_dec, b_inj, Aff);
    chunk_scan<<<dim3(GG / 4), dim3(256), 0, stream>>>(Aff, Hs);
    chunk_apply_out<<<dim3(CC, BB), dim3(128), 0, stream>>>(quat, Wc, b_biv, b_dec, b_inj,
                                                            W_out, Hs, out);
}

// Round 7
// 69.982 us; speedup vs baseline: 1.5564x; 1.1190x over previous
//
#include <hip/hip_runtime.h>
#include <hip/hip_bf16.h>

#define BB 16
#define TT 2048
#define DD 384
#define GG 2048          // total chains = BB * 128
#define CC 256           // chunks over T
#define LL 8             // steps per chunk (CC*LL == TT)
#define HSTRIDE (DD + 8) // 392 ≡ 8 (mod 32): conflict-free LDS access pattern
#define EPSF 1e-8f
#define RCPF(x) __builtin_amdgcn_rcpf(x)

// ---------- kernel 0: combined weights Wc[m][k][j] = sum_d W_in[k][d]*Wm[d][j] ----------
__global__ __launch_bounds__(256) void precompute_wc(
        const float* __restrict__ W_in,
        const float* __restrict__ W_biv,
        const float* __restrict__ W_dec,
        const float* __restrict__ W_inj,
        float* __restrict__ Wc) {
    int m = blockIdx.x;
    int jl = threadIdx.x & 15;
    int dp = threadIdx.x >> 4;           // 0..15
    int j = blockIdx.y * 16 + jl;
    const float* __restrict__ W = (m == 0) ? W_biv : (m == 1) ? W_dec : W_inj;
    float a[4] = {0.f, 0.f, 0.f, 0.f};
    for (int d = dp; d < DD; d += 16) {
        float wv = W[d * DD + j];
#pragma unroll
        for (int k = 0; k < 4; ++k) a[k] = fmaf(W_in[k * DD + d], wv, a[k]);
    }
    __shared__ float red[16][17][4];
#pragma unroll
    for (int k = 0; k < 4; ++k) red[dp][jl][k] = a[k];
    __syncthreads();
    for (int s = 8; s >= 1; s >>= 1) {
        if (dp < s) {
#pragma unroll
            for (int k = 0; k < 4; ++k) red[dp][jl][k] += red[dp + s][jl][k];
        }
        __syncthreads();
    }
    if (dp < 4)
        Wc[(size_t)m * 4 * DD + dp * DD + j] = red[0][jl][dp];
}

// ---------- shared per-step math ----------
#define LOAD_CHAIN_WEIGHTS()                                        \
    const float* __restrict__ Wb = Wc;                              \
    const float* __restrict__ Wd = Wc + 4 * DD;                     \
    const float* __restrict__ Wi = Wc + 8 * DD;                     \
    float wb[4][3], wd[4][3], wi[4][3];                             \
    _Pragma("unroll")                                               \
    for (int k = 0; k < 4; ++k)                                     \
        _Pragma("unroll")                                           \
        for (int cth = 0; cth < 3; ++cth) {                         \
            wb[k][cth] = Wb[k * DD + j0 + cth];                     \
            wd[k][cth] = Wd[k * DD + j0 + cth];                     \
            wi[k][cth] = Wi[k * DD + j0 + cth];                     \
        }                                                           \
    float bbv[3], bdv[3], bjv[3];                                   \
    _Pragma("unroll")                                               \
    for (int cth = 0; cth < 3; ++cth) {                             \
        bbv[cth] = b_biv[j0 + cth];                                 \
        bdv[cth] = b_dec[j0 + cth];                                 \
        bjv[cth] = b_inj[j0 + cth];                                 \
    }

#define DOT4(W, c, bias) \
    fmaf(q.w, W[3][c], fmaf(q.z, W[2][c], fmaf(q.y, W[1][c], fmaf(q.x, W[0][c], bias))))

#define STEP_COMMON()                                               \
    float bx = DOT4(wb, 0, bbv[0]);                                 \
    float by = DOT4(wb, 1, bbv[1]);                                 \
    float bz = DOT4(wb, 2, bbv[2]);                                 \
    float d0 = DOT4(wd, 0, bdv[0]);                                 \
    float d1 = DOT4(wd, 1, bdv[1]);                                 \
    float d2 = DOT4(wd, 2, bdv[2]);                                 \
    float i0 = DOT4(wi, 0, bjv[0]);                                 \
    float i1 = DOT4(wi, 1, bjv[1]);                                 \
    float i2 = DOT4(wi, 2, bjv[2]);                                 \
    float dec0 = RCPF(1.f + __expf(-d0));                           \
    float dec1 = RCPF(1.f + __expf(-d1));                           \
    float dec2 = RCPF(1.f + __expf(-d2));                           \
    float nb = fmaxf(sqrtf(fmaf(bx, bx, fmaf(by, by, bz * bz))), EPSF); \
    float half = 0.5f * nb;                                         \
    float w = __cosf(half);                                         \
    float s = __sinf(half) * RCPF(nb);                              \
    float qx = s * bz, qy = -s * by, qz = s * bx;

// ---------- kernel A: per-(chain, chunk) composed affine map ----------
// Aff layout: [CC][GG][12]
__global__ __launch_bounds__(128) void chunk_compose(
        const float* __restrict__ quat,
        const float* __restrict__ Wc,
        const float* __restrict__ b_biv,
        const float* __restrict__ b_dec,
        const float* __restrict__ b_inj,
        float* __restrict__ Aff) {
    int c = blockIdx.x, b = blockIdx.y, n = threadIdx.x;
    int g = b * 128 + n, j0 = 3 * n;
    LOAD_CHAIN_WEIGHTS();

    float A[3][3] = {{1.f,0.f,0.f},{0.f,1.f,0.f},{0.f,0.f,1.f}};
    float dv[3] = {0.f, 0.f, 0.f};

    const float4* __restrict__ qp4 = (const float4*)(quat + (size_t)b * TT * 4) + c * LL;

    for (int t = 0; t < LL; ++t) {
        float4 q = qp4[t];
        STEP_COMMON();
        float xx = qx*qx, yy = qy*qy, zz = qz*qz;
        float xy = qx*qy, xz = qx*qz, yz = qy*qz;
        float wxs = w*qx, wys = w*qy, wzs = w*qz;
        float M[3][3];
        M[0][0] = dec0 * (1.f - 2.f*(yy+zz));
        M[0][1] = dec0 * (2.f*(xy - wzs));
        M[0][2] = dec0 * (2.f*(xz + wys));
        M[1][0] = dec1 * (2.f*(xy + wzs));
        M[1][1] = dec1 * (1.f - 2.f*(xx+zz));
        M[1][2] = dec1 * (2.f*(yz - wxs));
        M[2][0] = dec2 * (2.f*(xz - wys));
        M[2][1] = dec2 * (2.f*(yz + wxs));
        M[2][2] = dec2 * (1.f - 2.f*(xx+yy));
        float nA[3][3], nd[3];
#pragma unroll
        for (int i = 0; i < 3; ++i) {
#pragma unroll
            for (int j = 0; j < 3; ++j)
                nA[i][j] = fmaf(M[i][0], A[0][j], fmaf(M[i][1], A[1][j], M[i][2] * A[2][j]));
            nd[i] = fmaf(M[i][0], dv[0], fmaf(M[i][1], dv[1], M[i][2] * dv[2]));
        }
        nd[0] += i0; nd[1] += i1; nd[2] += i2;
#pragma unroll
        for (int i = 0; i < 3; ++i) {
#pragma unroll
            for (int j = 0; j < 3; ++j) A[i][j] = nA[i][j];
            dv[i] = nd[i];
        }
    }
    float4* o = (float4*)(Aff + ((size_t)c * GG + g) * 12);
    o[0] = make_float4(A[0][0], A[0][1], A[0][2], A[1][0]);
    o[1] = make_float4(A[1][1], A[1][2], A[2][0], A[2][1]);
    o[2] = make_float4(A[2][2], dv[0], dv[1], dv[2]);
}

// ---------- kernel B: wave-parallel scan, 4 chunks per lane ----------
// lane l composes chunks 4l..4l+3; Kogge-Stone exclusive over quad maps;
// emits start states of all 4 chunks.
#define COMPOSE(R00,R01,R02,R10,R11,R12,R20,R21,R22,Rd0,Rd1,Rd2,            \
                C00,C01,C02,C10,C11,C12,C20,C21,C22,Cd0,Cd1,Cd2,            \
                P00,P01,P02,P10,P11,P12,P20,P21,P22,Pd0,Pd1,Pd2)            \
    R00 = fmaf(C00, P00, fmaf(C01, P10, C02 * P20));                        \
    R01 = fmaf(C00, P01, fmaf(C01, P11, C02 * P21));                        \
    R02 = fmaf(C00, P02, fmaf(C01, P12, C02 * P22));                        \
    R10 = fmaf(C10, P00, fmaf(C11, P10, C12 * P20));                        \
    R11 = fmaf(C10, P01, fmaf(C11, P11, C12 * P21));                        \
    R12 = fmaf(C10, P02, fmaf(C11, P12, C12 * P22));                        \
    R20 = fmaf(C20, P00, fmaf(C21, P10, C22 * P20));                        \
    R21 = fmaf(C20, P01, fmaf(C21, P11, C22 * P21));                        \
    R22 = fmaf(C20, P02, fmaf(C21, P12, C22 * P22));                        \
    Rd0 = fmaf(C00, Pd0, fmaf(C01, Pd1, fmaf(C02, Pd2, Cd0)));              \
    Rd1 = fmaf(C10, Pd0, fmaf(C11, Pd1, fmaf(C12, Pd2, Cd1)));              \
    Rd2 = fmaf(C20, Pd0, fmaf(C21, Pd1, fmaf(C22, Pd2, Cd2)));

__global__ __launch_bounds__(256) void chunk_scan(
        const float* __restrict__ Aff,
        float* __restrict__ Hs) {
    int g = (blockIdx.x * 256 + threadIdx.x) >> 6;   // chain
    int l = threadIdx.x & 63;                        // lane = quad index

    float m[4][12];   // individual chunk maps 4l..4l+3
#pragma unroll
    for (int k = 0; k < 4; ++k) {
        const float4* a = (const float4*)(Aff + ((size_t)(4 * l + k) * GG + g) * 12);
        float4 a0 = a[0], a1 = a[1], a2 = a[2];
        m[k][0]=a0.x; m[k][1]=a0.y; m[k][2]=a0.z; m[k][3]=a0.w;
        m[k][4]=a1.x; m[k][5]=a1.y; m[k][6]=a1.z; m[k][7]=a1.w;
        m[k][8]=a2.x; m[k][9]=a2.y; m[k][10]=a2.z; m[k][11]=a2.w;
    }
    // quad = m3 ∘ m2 ∘ m1 ∘ m0
    float q01[12], q012[12], Q[12];
    COMPOSE(q01[0],q01[1],q01[2],q01[3],q01[4],q01[5],q01[6],q01[7],q01[8],q01[9],q01[10],q01[11],
            m[1][0],m[1][1],m[1][2],m[1][3],m[1][4],m[1][5],m[1][6],m[1][7],m[1][8],m[1][9],m[1][10],m[1][11],
            m[0][0],m[0][1],m[0][2],m[0][3],m[0][4],m[0][5],m[0][6],m[0][7],m[0][8],m[0][9],m[0][10],m[0][11]);
    COMPOSE(q012[0],q012[1],q012[2],q012[3],q012[4],q012[5],q012[6],q012[7],q012[8],q012[9],q012[10],q012[11],
            m[2][0],m[2][1],m[2][2],m[2][3],m[2][4],m[2][5],m[2][6],m[2][7],m[2][8],m[2][9],m[2][10],m[2][11],
            q01[0],q01[1],q01[2],q01[3],q01[4],q01[5],q01[6],q01[7],q01[8],q01[9],q01[10],q01[11]);
    COMPOSE(Q[0],Q[1],Q[2],Q[3],Q[4],Q[5],Q[6],Q[7],Q[8],Q[9],Q[10],Q[11],
            m[3][0],m[3][1],m[3][2],m[3][3],m[3][4],m[3][5],m[3][6],m[3][7],m[3][8],m[3][9],m[3][10],m[3][11],
            q012[0],q012[1],q012[2],q012[3],q012[4],q012[5],q012[6],q012[7],q012[8],q012[9],q012[10],q012[11]);

    // exclusive shift by 1 lane
    float P[12];
#pragma unroll
    for (int k = 0; k < 12; ++k) P[k] = __shfl_up(Q[k], 1);
    if (l == 0) {
        P[0]=1.f; P[1]=0.f; P[2]=0.f; P[3]=0.f; P[4]=1.f; P[5]=0.f;
        P[6]=0.f; P[7]=0.f; P[8]=1.f; P[9]=0.f; P[10]=0.f; P[11]=0.f;
    }
#pragma unroll
    for (int sft = 1; sft < 64; sft <<= 1) {
        float S[12], N[12];
#pragma unroll
        for (int k = 0; k < 12; ++k) S[k] = __shfl_up(P[k], sft);
        COMPOSE(N[0],N[1],N[2],N[3],N[4],N[5],N[6],N[7],N[8],N[9],N[10],N[11],
                P[0],P[1],P[2],P[3],P[4],P[5],P[6],P[7],P[8],P[9],P[10],P[11],
                S[0],S[1],S[2],S[3],S[4],S[5],S[6],S[7],S[8],S[9],S[10],S[11]);
        bool act = (l >= sft);
#pragma unroll
        for (int k = 0; k < 12; ++k) P[k] = act ? N[k] : P[k];
    }

    // emit start states: h(4l) = P.d; then step through m0..m2
    float h0 = P[9], h1 = P[10], h2 = P[11];
#pragma unroll
    for (int k = 0; k < 4; ++k) {
        float* hs = Hs + ((size_t)(4 * l + k) * GG + g) * 3;
        hs[0] = h0; hs[1] = h1; hs[2] = h2;
        if (k < 3) {
            float n0 = fmaf(m[k][0], h0, fmaf(m[k][1], h1, fmaf(m[k][2], h2, m[k][9])));
            float n1 = fmaf(m[k][3], h0, fmaf(m[k][4], h1, fmaf(m[k][5], h2, m[k][10])));
            float n2 = fmaf(m[k][6], h0, fmaf(m[k][7], h1, fmaf(m[k][8], h2, m[k][11])));
            h0 = n0; h1 = n1; h2 = n2;
        }
    }
}

// ---------- kernel C: fused replay + out-projection via LDS, ONE barrier ----------
__global__ __launch_bounds__(128) void chunk_apply_out(
        const float* __restrict__ quat,
        const float* __restrict__ Wc,
        const float* __restrict__ b_biv,
        const float* __restrict__ b_dec,
        const float* __restrict__ b_inj,
        const float* __restrict__ W_out,   // [DD][4]
        const float* __restrict__ Hs,      // [CC][GG][3]
        float* __restrict__ out) {         // [BB][TT][4]
    int c = blockIdx.x, b = blockIdx.y, n = threadIdx.x;
    int g = b * 128 + n, j0 = 3 * n;
    LOAD_CHAIN_WEIGHTS();

    __shared__ float H[LL][HSTRIDE];

    const float* hs = Hs + ((size_t)c * GG + g) * 3;
    float vx = hs[0], vy = hs[1], vz = hs[2];

    const float4* __restrict__ qp4 = (const float4*)(quat + (size_t)b * TT * 4) + c * LL;

    for (int t = 0; t < LL; ++t) {
        float4 q = qp4[t];
        STEP_COMMON();
        float tx = 2.f * (qy * vz - qz * vy);
        float ty = 2.f * (qz * vx - qx * vz);
        float tz = 2.f * (qx * vy - qy * vx);
        float rx = vx + w * tx + (qy * tz - qz * ty);
        float ry = vy + w * ty + (qz * tx - qx * tz);
        float rz = vz + w * tz + (qx * ty - qy * tx);
        vx = fmaf(dec0, rx, i0);
        vy = fmaf(dec1, ry, i1);
        vz = fmaf(dec2, rz, i2);
        H[t][j0] = vx; H[t][j0 + 1] = vy; H[t][j0 + 2] = vz;
    }
    __syncthreads();

    // projection: thread -> (row r, part p); d = p + 16j
    int r = n >> 4, p = n & 15;
    float s0 = 0.f, s1 = 0.f, s2 = 0.f, s3 = 0.f;
#pragma unroll 8
    for (int j = 0; j < DD / 16; ++j) {
        int d = p + 16 * j;
        float hv = H[r][d];
        float4 wv = *(const float4*)(W_out + (size_t)d * 4);
        s0 = fmaf(hv, wv.x, s0);
        s1 = fmaf(hv, wv.y, s1);
        s2 = fmaf(hv, wv.z, s2);
        s3 = fmaf(hv, wv.w, s3);
    }
#pragma unroll
    for (int off = 1; off <= 8; off <<= 1) {
        s0 += __shfl_xor(s0, off);
        s1 += __shfl_xor(s1, off);
        s2 += __shfl_xor(s2, off);
        s3 += __shfl_xor(s3, off);
    }
    if (p == 0) {
        float norm = fmaxf(sqrtf(fmaf(s0, s0, fmaf(s1, s1, fmaf(s2, s2, s3 * s3)))), EPSF);
        float inv = RCPF(norm);
        float* outp = out + ((size_t)b * TT + (size_t)c * LL + r) * 4;
        *(float4*)outp = make_float4(s0 * inv, s1 * inv, s2 * inv, s3 * inv);
    }
}

extern "C" void kernel_launch(void* const* d_in, const int* in_sizes, int n_in,
                              void* d_out, int out_size, void* d_ws, size_t ws_size,
                              hipStream_t stream) {
    const float* quat  = (const float*)d_in[0];
    const float* W_in  = (const float*)d_in[1];
    const float* W_biv = (const float*)d_in[2];
    const float* b_biv = (const float*)d_in[3];
    const float* W_dec = (const float*)d_in[4];
    const float* b_dec = (const float*)d_in[5];
    const float* W_inj = (const float*)d_in[6];
    const float* b_inj = (const float*)d_in[7];
    const float* W_out = (const float*)d_in[8];
    float* out = (float*)d_out;

    const size_t AFF_OFF = 32768;                                  // Wc: 18432 B
    const size_t AFF_B   = (size_t)CC * GG * 12 * sizeof(float);   // 25.2 MB
    const size_t HS_OFF  = AFF_OFF + AFF_B;

    float* Wc  = (float*)d_ws;
    float* Aff = (float*)((char*)d_ws + AFF_OFF);
    float* Hs  = (float*)((char*)d_ws + HS_OFF);

    precompute_wc<<<dim3(3, DD / 16), dim3(256), 0, stream>>>(W_in, W_biv, W_dec, W_inj, Wc);
    chunk_compose<<<dim3(CC, BB), dim3(128), 0, stream>>>(quat, Wc, b_biv, b_dec, b_inj, Aff);
    chunk_scan<<<dim3(GG / 4), dim3(256), 0, stream>>>(Aff, Hs);
    chunk_apply_out<<<dim3(CC, BB), dim3(128), 0, stream>>>(quat, Wc, b_biv, b_dec, b_inj,
                                                            W_out, Hs, out);
}

// Round 8
// 65.583 us; speedup vs baseline: 1.6608x; 1.0671x over previous
//
#include <hip/hip_runtime.h>
#include <hip/hip_bf16.h>

#define BB 16
#define TT 2048
#define DD 384
#define GG 2048          // total chains = BB * 128
#define CC 256           // chunks over T
#define LL 8             // steps per chunk (CC*LL == TT)
#define HSTRIDE (DD + 8) // 392 ≡ 8 (mod 32): conflict-free LDS access
#define EPSF 1e-8f
#define RCPF(x) __builtin_amdgcn_rcpf(x)

// ---------- kernel 0: combined weights Wc[m][k][j] = sum_d W_in[k][d]*Wm[d][j] ----------
__global__ __launch_bounds__(256) void precompute_wc(
        const float* __restrict__ W_in,
        const float* __restrict__ W_biv,
        const float* __restrict__ W_dec,
        const float* __restrict__ W_inj,
        float* __restrict__ Wc) {
    int m = blockIdx.x;
    int jl = threadIdx.x & 15;
    int dp = threadIdx.x >> 4;           // 0..15
    int j = blockIdx.y * 16 + jl;
    const float* __restrict__ W = (m == 0) ? W_biv : (m == 1) ? W_dec : W_inj;
    float a[4] = {0.f, 0.f, 0.f, 0.f};
    for (int d = dp; d < DD; d += 16) {
        float wv = W[d * DD + j];
#pragma unroll
        for (int k = 0; k < 4; ++k) a[k] = fmaf(W_in[k * DD + d], wv, a[k]);
    }
    __shared__ float red[16][17][4];
#pragma unroll
    for (int k = 0; k < 4; ++k) red[dp][jl][k] = a[k];
    __syncthreads();
    for (int s = 8; s >= 1; s >>= 1) {
        if (dp < s) {
#pragma unroll
            for (int k = 0; k < 4; ++k) red[dp][jl][k] += red[dp + s][jl][k];
        }
        __syncthreads();
    }
    if (dp < 4)
        Wc[(size_t)m * 4 * DD + dp * DD + j] = red[0][jl][dp];
}

// ---------- per-chain weights & per-step math (polynomial trig, no sqrt/sin/cos) ----------
struct Wts {
    float wb[4][3], wd[4][3], wi[4][3];
    float bb[3], bd[3], bj[3];
};

__device__ __forceinline__ void load_wts(const float* __restrict__ Wc,
                                         const float* __restrict__ b_biv,
                                         const float* __restrict__ b_dec,
                                         const float* __restrict__ b_inj,
                                         int j0, Wts& W) {
    const float* __restrict__ Wb = Wc;
    const float* __restrict__ Wd = Wc + 4 * DD;
    const float* __restrict__ Wi = Wc + 8 * DD;
#pragma unroll
    for (int k = 0; k < 4; ++k)
#pragma unroll
        for (int c = 0; c < 3; ++c) {
            W.wb[k][c] = Wb[k * DD + j0 + c];
            W.wd[k][c] = Wd[k * DD + j0 + c];
            W.wi[k][c] = Wi[k * DD + j0 + c];
        }
#pragma unroll
    for (int c = 0; c < 3; ++c) {
        W.bb[c] = b_biv[j0 + c];
        W.bd[c] = b_dec[j0 + c];
        W.bj[c] = b_inj[j0 + c];
    }
}

#define DOTW(M, c, bias) \
    fmaf(q.w, W.M[3][c], fmaf(q.z, W.M[2][c], fmaf(q.y, W.M[1][c], fmaf(q.x, W.M[0][c], bias))))

// w = cos(nb/2) = 1 - u/8 + u^2/384 ; s = sin(nb/2)/nb = 1/2 - u/48 + u^2/3840 ; u = nb^2.
// Exact in the EPS-clamp limit (s->1/2). R = I + 2w[q]x + 2(qq^T - |q|^2 I) is exact for any (w,q).
__device__ __forceinline__ void step_parts(const Wts& W, float4 q,
        float& dec0, float& dec1, float& dec2,
        float& w, float& qx, float& qy, float& qz,
        float& i0, float& i1, float& i2) {
    float bx = DOTW(wb, 0, W.bb[0]);
    float by = DOTW(wb, 1, W.bb[1]);
    float bz = DOTW(wb, 2, W.bb[2]);
    float d0 = DOTW(wd, 0, W.bd[0]);
    float d1 = DOTW(wd, 1, W.bd[1]);
    float d2 = DOTW(wd, 2, W.bd[2]);
    i0 = DOTW(wi, 0, W.bj[0]);
    i1 = DOTW(wi, 1, W.bj[1]);
    i2 = DOTW(wi, 2, W.bj[2]);
    dec0 = RCPF(1.f + __expf(-d0));
    dec1 = RCPF(1.f + __expf(-d1));
    dec2 = RCPF(1.f + __expf(-d2));
    float u = fmaf(bx, bx, fmaf(by, by, bz * bz));
    w = fmaf(u, fmaf(u, 2.6041667e-3f, -0.125f), 1.f);
    float s = fmaf(u, fmaf(u, 2.6041667e-4f, -2.0833333e-2f), 0.5f);
    qx = s * bz; qy = -s * by; qz = s * bx;
}

__device__ __forceinline__ void step_compose(const Wts& W, float4 q,
                                             float A[3][3], float dv[3]) {
    float dec0, dec1, dec2, w, qx, qy, qz, i0, i1, i2;
    step_parts(W, q, dec0, dec1, dec2, w, qx, qy, qz, i0, i1, i2);
    float xx = qx*qx, yy = qy*qy, zz = qz*qz;
    float xy = qx*qy, xz = qx*qz, yz = qy*qz;
    float wxs = w*qx, wys = w*qy, wzs = w*qz;
    float M[3][3];
    M[0][0] = dec0 * (1.f - 2.f*(yy+zz));
    M[0][1] = dec0 * (2.f*(xy - wzs));
    M[0][2] = dec0 * (2.f*(xz + wys));
    M[1][0] = dec1 * (2.f*(xy + wzs));
    M[1][1] = dec1 * (1.f - 2.f*(xx+zz));
    M[1][2] = dec1 * (2.f*(yz - wxs));
    M[2][0] = dec2 * (2.f*(xz - wys));
    M[2][1] = dec2 * (2.f*(yz + wxs));
    M[2][2] = dec2 * (1.f - 2.f*(xx+yy));
    float nA[3][3], nd[3];
#pragma unroll
    for (int i = 0; i < 3; ++i) {
#pragma unroll
        for (int j = 0; j < 3; ++j)
            nA[i][j] = fmaf(M[i][0], A[0][j], fmaf(M[i][1], A[1][j], M[i][2] * A[2][j]));
        nd[i] = fmaf(M[i][0], dv[0], fmaf(M[i][1], dv[1], M[i][2] * dv[2]));
    }
    nd[0] += i0; nd[1] += i1; nd[2] += i2;
#pragma unroll
    for (int i = 0; i < 3; ++i) {
#pragma unroll
        for (int j = 0; j < 3; ++j) A[i][j] = nA[i][j];
        dv[i] = nd[i];
    }
}

__device__ __forceinline__ void step_apply(const Wts& W, float4 q,
                                           float& vx, float& vy, float& vz) {
    float dec0, dec1, dec2, w, qx, qy, qz, i0, i1, i2;
    step_parts(W, q, dec0, dec1, dec2, w, qx, qy, qz, i0, i1, i2);
    float tx = 2.f * (qy * vz - qz * vy);
    float ty = 2.f * (qz * vx - qx * vz);
    float tz = 2.f * (qx * vy - qy * vx);
    float rx = vx + w * tx + (qy * tz - qz * ty);
    float ry = vy + w * ty + (qz * tx - qx * tz);
    float rz = vz + w * tz + (qx * ty - qy * tx);
    vx = fmaf(dec0, rx, i0);
    vy = fmaf(dec1, ry, i1);
    vz = fmaf(dec2, rz, i2);
}

// ---------- kernel A: composed affine maps; 2 chunks per thread (ILP) ----------
// Aff layout: [CC][GG][12]
__global__ __launch_bounds__(128) void chunk_compose(
        const float* __restrict__ quat,
        const float* __restrict__ Wc,
        const float* __restrict__ b_biv,
        const float* __restrict__ b_dec,
        const float* __restrict__ b_inj,
        float* __restrict__ Aff) {
    int c = blockIdx.x;               // 0..CC/2-1; handles chunks c and c+CC/2
    int b = blockIdx.y, n = threadIdx.x;
    int g = b * 128 + n, j0 = 3 * n;
    Wts W;
    load_wts(Wc, b_biv, b_dec, b_inj, j0, W);

    float A1[3][3] = {{1.f,0.f,0.f},{0.f,1.f,0.f},{0.f,0.f,1.f}};
    float d1[3] = {0.f, 0.f, 0.f};
    float A2[3][3] = {{1.f,0.f,0.f},{0.f,1.f,0.f},{0.f,0.f,1.f}};
    float d2[3] = {0.f, 0.f, 0.f};

    const float4* __restrict__ qpA = (const float4*)(quat + (size_t)b * TT * 4) + c * LL;
    const float4* __restrict__ qpB = qpA + (CC / 2) * LL;

#pragma unroll
    for (int t = 0; t < LL; ++t) {
        step_compose(W, qpA[t], A1, d1);
        step_compose(W, qpB[t], A2, d2);
    }
    float4* o1 = (float4*)(Aff + ((size_t)c * GG + g) * 12);
    o1[0] = make_float4(A1[0][0], A1[0][1], A1[0][2], A1[1][0]);
    o1[1] = make_float4(A1[1][1], A1[1][2], A1[2][0], A1[2][1]);
    o1[2] = make_float4(A1[2][2], d1[0], d1[1], d1[2]);
    float4* o2 = (float4*)(Aff + ((size_t)(c + CC / 2) * GG + g) * 12);
    o2[0] = make_float4(A2[0][0], A2[0][1], A2[0][2], A2[1][0]);
    o2[1] = make_float4(A2[1][1], A2[1][2], A2[2][0], A2[2][1]);
    o2[2] = make_float4(A2[2][2], d2[0], d2[1], d2[2]);
}

// ---------- kernel B: wave-parallel scan, 4 chunks per lane ----------
#define COMPOSE(R, C, P)                                                    \
    R[0] = fmaf(C[0], P[0], fmaf(C[1], P[3], C[2] * P[6]));                 \
    R[1] = fmaf(C[0], P[1], fmaf(C[1], P[4], C[2] * P[7]));                 \
    R[2] = fmaf(C[0], P[2], fmaf(C[1], P[5], C[2] * P[8]));                 \
    R[3] = fmaf(C[3], P[0], fmaf(C[4], P[3], C[5] * P[6]));                 \
    R[4] = fmaf(C[3], P[1], fmaf(C[4], P[4], C[5] * P[7]));                 \
    R[5] = fmaf(C[3], P[2], fmaf(C[4], P[5], C[5] * P[8]));                 \
    R[6] = fmaf(C[6], P[0], fmaf(C[7], P[3], C[8] * P[6]));                 \
    R[7] = fmaf(C[6], P[1], fmaf(C[7], P[4], C[8] * P[7]));                 \
    R[8] = fmaf(C[6], P[2], fmaf(C[7], P[5], C[8] * P[8]));                 \
    R[9]  = fmaf(C[0], P[9], fmaf(C[1], P[10], fmaf(C[2], P[11], C[9])));   \
    R[10] = fmaf(C[3], P[9], fmaf(C[4], P[10], fmaf(C[5], P[11], C[10])));  \
    R[11] = fmaf(C[6], P[9], fmaf(C[7], P[10], fmaf(C[8], P[11], C[11])));

__global__ __launch_bounds__(256) void chunk_scan(
        const float* __restrict__ Aff,
        float* __restrict__ Hs) {
    int g = (blockIdx.x * 256 + threadIdx.x) >> 6;   // chain
    int l = threadIdx.x & 63;                        // lane = quad index

    float m[4][12];
#pragma unroll
    for (int k = 0; k < 4; ++k) {
        const float4* a = (const float4*)(Aff + ((size_t)(4 * l + k) * GG + g) * 12);
        float4 a0 = a[0], a1 = a[1], a2 = a[2];
        m[k][0]=a0.x; m[k][1]=a0.y; m[k][2]=a0.z; m[k][3]=a0.w;
        m[k][4]=a1.x; m[k][5]=a1.y; m[k][6]=a1.z; m[k][7]=a1.w;
        m[k][8]=a2.x; m[k][9]=a2.y; m[k][10]=a2.z; m[k][11]=a2.w;
    }
    float q01[12], q012[12], Q[12];
    COMPOSE(q01, m[1], m[0]);
    COMPOSE(q012, m[2], q01);
    COMPOSE(Q, m[3], q012);

    float P[12];
#pragma unroll
    for (int k = 0; k < 12; ++k) P[k] = __shfl_up(Q[k], 1);
    if (l == 0) {
        P[0]=1.f; P[1]=0.f; P[2]=0.f; P[3]=0.f; P[4]=1.f; P[5]=0.f;
        P[6]=0.f; P[7]=0.f; P[8]=1.f; P[9]=0.f; P[10]=0.f; P[11]=0.f;
    }
#pragma unroll
    for (int sft = 1; sft < 64; sft <<= 1) {
        float S[12], N[12];
#pragma unroll
        for (int k = 0; k < 12; ++k) S[k] = __shfl_up(P[k], sft);
        COMPOSE(N, P, S);
        bool act = (l >= sft);
#pragma unroll
        for (int k = 0; k < 12; ++k) P[k] = act ? N[k] : P[k];
    }

    float h0 = P[9], h1 = P[10], h2 = P[11];
#pragma unroll
    for (int k = 0; k < 4; ++k) {
        float* hs = Hs + ((size_t)(4 * l + k) * GG + g) * 3;
        hs[0] = h0; hs[1] = h1; hs[2] = h2;
        if (k < 3) {
            float n0 = fmaf(m[k][0], h0, fmaf(m[k][1], h1, fmaf(m[k][2], h2, m[k][9])));
            float n1 = fmaf(m[k][3], h0, fmaf(m[k][4], h1, fmaf(m[k][5], h2, m[k][10])));
            float n2 = fmaf(m[k][6], h0, fmaf(m[k][7], h1, fmaf(m[k][8], h2, m[k][11])));
            h0 = n0; h1 = n1; h2 = n2;
        }
    }
}

// ---------- kernel C: fused replay + out-projection via LDS, ONE barrier ----------
__global__ __launch_bounds__(128) void chunk_apply_out(
        const float* __restrict__ quat,
        const float* __restrict__ Wc,
        const float* __restrict__ b_biv,
        const float* __restrict__ b_dec,
        const float* __restrict__ b_inj,
        const float* __restrict__ W_out,   // [DD][4]
        const float* __restrict__ Hs,      // [CC][GG][3]
        float* __restrict__ out) {         // [BB][TT][4]
    int c = blockIdx.x, b = blockIdx.y, n = threadIdx.x;
    int g = b * 128 + n, j0 = 3 * n;
    Wts W;
    load_wts(Wc, b_biv, b_dec, b_inj, j0, W);

    __shared__ float H[LL][HSTRIDE];

    const float* hs = Hs + ((size_t)c * GG + g) * 3;
    float vx = hs[0], vy = hs[1], vz = hs[2];

    const float4* __restrict__ qp4 = (const float4*)(quat + (size_t)b * TT * 4) + c * LL;

#pragma unroll
    for (int t = 0; t < LL; ++t) {
        step_apply(W, qp4[t], vx, vy, vz);
        H[t][j0] = vx; H[t][j0 + 1] = vy; H[t][j0 + 2] = vz;
    }
    __syncthreads();

    // projection: thread -> (row r, part p); d = p + 16j
    int r = n >> 4, p = n & 15;
    float s0 = 0.f, s1 = 0.f, s2 = 0.f, s3 = 0.f;
#pragma unroll 8
    for (int j = 0; j < DD / 16; ++j) {
        int d = p + 16 * j;
        float hv = H[r][d];
        float4 wv = *(const float4*)(W_out + (size_t)d * 4);
        s0 = fmaf(hv, wv.x, s0);
        s1 = fmaf(hv, wv.y, s1);
        s2 = fmaf(hv, wv.z, s2);
        s3 = fmaf(hv, wv.w, s3);
    }
#pragma unroll
    for (int off = 1; off <= 8; off <<= 1) {
        s0 += __shfl_xor(s0, off);
        s1 += __shfl_xor(s1, off);
        s2 += __shfl_xor(s2, off);
        s3 += __shfl_xor(s3, off);
    }
    if (p == 0) {
        float norm = fmaxf(sqrtf(fmaf(s0, s0, fmaf(s1, s1, fmaf(s2, s2, s3 * s3)))), EPSF);
        float inv = RCPF(norm);
        float* outp = out + ((size_t)b * TT + (size_t)c * LL + r) * 4;
        *(float4*)outp = make_float4(s0 * inv, s1 * inv, s2 * inv, s3 * inv);
    }
}

extern "C" void kernel_launch(void* const* d_in, const int* in_sizes, int n_in,
                              void* d_out, int out_size, void* d_ws, size_t ws_size,
                              hipStream_t stream) {
    const float* quat  = (const float*)d_in[0];
    const float* W_in  = (const float*)d_in[1];
    const float* W_biv = (const float*)d_in[2];
    const float* b_biv = (const float*)d_in[3];
    const float* W_dec = (const float*)d_in[4];
    const float* b_dec = (const float*)d_in[5];
    const float* W_inj = (const float*)d_in[6];
    const float* b_inj = (const float*)d_in[7];
    const float* W_out = (const float*)d_in[8];
    float* out = (float*)d_out;

    const size_t AFF_OFF = 32768;                                  // Wc: 18432 B
    const size_t AFF_B   = (size_t)CC * GG * 12 * sizeof(float);   // 25.2 MB
    const size_t HS_OFF  = AFF_OFF + AFF_B;

    float* Wc  = (float*)d_ws;
    float* Aff = (float*)((char*)d_ws + AFF_OFF);
    float* Hs  = (float*)((char*)d_ws + HS_OFF);

    precompute_wc<<<dim3(3, DD / 16), dim3(256), 0, stream>>>(W_in, W_biv, W_dec, W_inj, Wc);
    chunk_compose<<<dim3(CC / 2, BB), dim3(128), 0, stream>>>(quat, Wc, b_biv, b_dec, b_inj, Aff);
    chunk_scan<<<dim3(GG / 4), dim3(256), 0, stream>>>(Aff, Hs);
    chunk_apply_out<<<dim3(CC, BB), dim3(128), 0, stream>>>(quat, Wc, b_biv, b_dec, b_inj,
                                                            W_out, Hs, out);
}